// Round 1
// baseline (371.600 us; speedup 1.0000x reference)
//
#include <hip/hip_runtime.h>

#define N_ROWS 4096
#define DIM 1024
#define INV_T (1.0f / 0.07f)

typedef __attribute__((ext_vector_type(8))) short short8;
typedef __attribute__((ext_vector_type(4))) float floatx4;

// round-to-nearest-even fp32 -> bf16 (finite inputs only)
__device__ inline unsigned short f2bf(float x) {
    unsigned int u = __float_as_uint(x);
    unsigned int r = (u + 0x7fffu + ((u >> 16) & 1u)) >> 16;
    return (unsigned short)r;
}

// One block per row: computes |z1|, |z2|, <z1,z2>, writes bf16 normalized rows
// and the exact fp32 diagonal logit.
__global__ __launch_bounds__(256) void k_normalize(
    const float* __restrict__ z1, const float* __restrict__ z2,
    unsigned short* __restrict__ z1b, unsigned short* __restrict__ z2b,
    float* __restrict__ diag) {
    const int row = blockIdx.x;
    const int t = threadIdx.x;
    const int lane = t & 63, wave = t >> 6;

    const float4 a = reinterpret_cast<const float4*>(z1 + (size_t)row * DIM)[t];
    const float4 b = reinterpret_cast<const float4*>(z2 + (size_t)row * DIM)[t];

    float s11 = a.x * a.x + a.y * a.y + a.z * a.z + a.w * a.w;
    float s22 = b.x * b.x + b.y * b.y + b.z * b.z + b.w * b.w;
    float s12 = a.x * b.x + a.y * b.y + a.z * b.z + a.w * b.w;

    #pragma unroll
    for (int m = 32; m >= 1; m >>= 1) {
        s11 += __shfl_xor(s11, m, 64);
        s22 += __shfl_xor(s22, m, 64);
        s12 += __shfl_xor(s12, m, 64);
    }

    __shared__ float r11[4], r22[4], r12[4];
    __shared__ float sh_inv1, sh_inv2;
    if (lane == 0) { r11[wave] = s11; r22[wave] = s22; r12[wave] = s12; }
    __syncthreads();
    if (t == 0) {
        float t11 = r11[0] + r11[1] + r11[2] + r11[3];
        float t22 = r22[0] + r22[1] + r22[2] + r22[3];
        float t12 = r12[0] + r12[1] + r12[2] + r12[3];
        float n1 = fmaxf(sqrtf(t11), 1e-12f);
        float n2 = fmaxf(sqrtf(t22), 1e-12f);
        diag[row] = t12 / (n1 * n2) * INV_T;
        sh_inv1 = 1.0f / n1;
        sh_inv2 = 1.0f / n2;
    }
    __syncthreads();
    const float i1 = sh_inv1, i2 = sh_inv2;

    ushort4 pa, pb;
    pa.x = f2bf(a.x * i1); pa.y = f2bf(a.y * i1);
    pa.z = f2bf(a.z * i1); pa.w = f2bf(a.w * i1);
    pb.x = f2bf(b.x * i2); pb.y = f2bf(b.y * i2);
    pb.z = f2bf(b.z * i2); pb.w = f2bf(b.w * i2);
    reinterpret_cast<ushort4*>(z1b)[(size_t)row * (DIM / 4) + t] = pa;
    reinterpret_cast<ushort4*>(z2b)[(size_t)row * (DIM / 4) + t] = pb;
}

// Tiled MFMA GEMM: block = 64 i-rows x 64 j-cols, 4 waves (each wave 16 rows x 64 cols).
// logits = z1n @ z2n^T / T; fuse exp + row-sum; atomicAdd partial sums into S[i].
// A-frag layout: A[m = lane&15][k = (lane>>4)*8 + j]; B (=z2n rows, i.e. B^T row-major)
// uses the same layout. C/D layout: col = lane&15, row = (lane>>4)*4 + reg.
__global__ __launch_bounds__(256) void k_gemm_sumexp(
    const unsigned short* __restrict__ z1b, const unsigned short* __restrict__ z2b,
    float* __restrict__ S) {
    const int jT = blockIdx.x, iT = blockIdx.y;
    const int lane = threadIdx.x & 63, wave = threadIdx.x >> 6;
    const int ml = lane & 15, q = lane >> 4;
    const int i0 = iT * 64 + wave * 16;
    const int j0 = jT * 64;

    floatx4 acc0 = {0.f, 0.f, 0.f, 0.f};
    floatx4 acc1 = {0.f, 0.f, 0.f, 0.f};
    floatx4 acc2 = {0.f, 0.f, 0.f, 0.f};
    floatx4 acc3 = {0.f, 0.f, 0.f, 0.f};

    const short8* A  = reinterpret_cast<const short8*>(z1b + (size_t)(i0 + ml) * DIM + q * 8);
    const short8* B0 = reinterpret_cast<const short8*>(z2b + (size_t)(j0 +  0 + ml) * DIM + q * 8);
    const short8* B1 = reinterpret_cast<const short8*>(z2b + (size_t)(j0 + 16 + ml) * DIM + q * 8);
    const short8* B2 = reinterpret_cast<const short8*>(z2b + (size_t)(j0 + 32 + ml) * DIM + q * 8);
    const short8* B3 = reinterpret_cast<const short8*>(z2b + (size_t)(j0 + 48 + ml) * DIM + q * 8);

    #pragma unroll 4
    for (int k = 0; k < DIM; k += 32) {
        const int ko = k >> 3;  // offset in short8 units
        short8 a = A[ko];
        acc0 = __builtin_amdgcn_mfma_f32_16x16x32_bf16(a, B0[ko], acc0, 0, 0, 0);
        acc1 = __builtin_amdgcn_mfma_f32_16x16x32_bf16(a, B1[ko], acc1, 0, 0, 0);
        acc2 = __builtin_amdgcn_mfma_f32_16x16x32_bf16(a, B2[ko], acc2, 0, 0, 0);
        acc3 = __builtin_amdgcn_mfma_f32_16x16x32_bf16(a, B3[ko], acc3, 0, 0, 0);
    }

    // epilogue: exp + row-sum over the wave's 64 columns, then atomic into S
    #pragma unroll
    for (int r = 0; r < 4; ++r) {
        float v = __expf(acc0[r] * INV_T) + __expf(acc1[r] * INV_T)
                + __expf(acc2[r] * INV_T) + __expf(acc3[r] * INV_T);
        v += __shfl_xor(v, 1, 64);
        v += __shfl_xor(v, 2, 64);
        v += __shfl_xor(v, 4, 64);
        v += __shfl_xor(v, 8, 64);
        if (ml == 0) atomicAdd(&S[i0 + q * 4 + r], v);
    }
}

__global__ __launch_bounds__(256) void k_finalize(
    const float* __restrict__ S, const float* __restrict__ diag,
    float* __restrict__ out) {
    const int t = threadIdx.x;
    float acc = 0.f;
    for (int i = t; i < N_ROWS; i += 256)
        acc += logf(S[i]) - diag[i];
    #pragma unroll
    for (int m = 32; m >= 1; m >>= 1)
        acc += __shfl_xor(acc, m, 64);
    __shared__ float r[4];
    if ((t & 63) == 0) r[t >> 6] = acc;
    __syncthreads();
    if (t == 0) out[0] = (r[0] + r[1] + r[2] + r[3]) / (float)N_ROWS;
}

extern "C" void kernel_launch(void* const* d_in, const int* in_sizes, int n_in,
                              void* d_out, int out_size, void* d_ws, size_t ws_size,
                              hipStream_t stream) {
    const float* z1 = (const float*)d_in[0];
    const float* z2 = (const float*)d_in[1];

    char* ws = (char*)d_ws;
    unsigned short* z1b = (unsigned short*)ws;                                   // 8 MB
    unsigned short* z2b = (unsigned short*)(ws + (size_t)N_ROWS * DIM * 2);      // 8 MB
    float* diag = (float*)(ws + (size_t)N_ROWS * DIM * 4);                       // 16 KB
    float* S = diag + N_ROWS;                                                    // 16 KB

    hipMemsetAsync(S, 0, N_ROWS * sizeof(float), stream);
    k_normalize<<<N_ROWS, 256, 0, stream>>>(z1, z2, z1b, z2b, diag);
    k_gemm_sumexp<<<dim3(64, 64), 256, 0, stream>>>(z1b, z2b, S);
    k_finalize<<<1, 256, 0, stream>>>(S, diag, (float*)d_out);
}

// Round 2
// 141.948 us; speedup vs baseline: 2.6179x; 2.6179x over previous
//
#include <hip/hip_runtime.h>

#define N_ROWS 4096
#define DIM 1024
#define INV_T (1.0f / 0.07f)
#define BK 32

typedef __attribute__((ext_vector_type(8))) short short8;
typedef __attribute__((ext_vector_type(4))) float floatx4;

// round-to-nearest-even fp32 -> bf16 (finite inputs only)
__device__ inline unsigned short f2bf(float x) {
    unsigned int u = __float_as_uint(x);
    unsigned int r = (u + 0x7fffu + ((u >> 16) & 1u)) >> 16;
    return (unsigned short)r;
}

// One block per row: computes |z1|, |z2|, <z1,z2>, writes bf16 normalized rows
// and the exact fp32 diagonal logit.
__global__ __launch_bounds__(256) void k_normalize(
    const float* __restrict__ z1, const float* __restrict__ z2,
    unsigned short* __restrict__ z1b, unsigned short* __restrict__ z2b,
    float* __restrict__ diag) {
    const int row = blockIdx.x;
    const int t = threadIdx.x;
    const int lane = t & 63, wave = t >> 6;

    const float4 a = reinterpret_cast<const float4*>(z1 + (size_t)row * DIM)[t];
    const float4 b = reinterpret_cast<const float4*>(z2 + (size_t)row * DIM)[t];

    float s11 = a.x * a.x + a.y * a.y + a.z * a.z + a.w * a.w;
    float s22 = b.x * b.x + b.y * b.y + b.z * b.z + b.w * b.w;
    float s12 = a.x * b.x + a.y * b.y + a.z * b.z + a.w * b.w;

    #pragma unroll
    for (int m = 32; m >= 1; m >>= 1) {
        s11 += __shfl_xor(s11, m, 64);
        s22 += __shfl_xor(s22, m, 64);
        s12 += __shfl_xor(s12, m, 64);
    }

    __shared__ float r11[4], r22[4], r12[4];
    __shared__ float sh_inv1, sh_inv2;
    if (lane == 0) { r11[wave] = s11; r22[wave] = s22; r12[wave] = s12; }
    __syncthreads();
    if (t == 0) {
        float t11 = r11[0] + r11[1] + r11[2] + r11[3];
        float t22 = r22[0] + r22[1] + r22[2] + r22[3];
        float t12 = r12[0] + r12[1] + r12[2] + r12[3];
        float n1 = fmaxf(sqrtf(t11), 1e-12f);
        float n2 = fmaxf(sqrtf(t22), 1e-12f);
        diag[row] = t12 / (n1 * n2) * INV_T;
        sh_inv1 = 1.0f / n1;
        sh_inv2 = 1.0f / n2;
    }
    __syncthreads();
    const float i1 = sh_inv1, i2 = sh_inv2;

    ushort4 pa, pb;
    pa.x = f2bf(a.x * i1); pa.y = f2bf(a.y * i1);
    pa.z = f2bf(a.z * i1); pa.w = f2bf(a.w * i1);
    pb.x = f2bf(b.x * i2); pb.y = f2bf(b.y * i2);
    pb.z = f2bf(b.z * i2); pb.w = f2bf(b.w * i2);
    reinterpret_cast<ushort4*>(z1b)[(size_t)row * (DIM / 4) + t] = pa;
    reinterpret_cast<ushort4*>(z2b)[(size_t)row * (DIM / 4) + t] = pb;
}

// m97-structure MFMA GEMM with fused softmax-denominator epilogue.
// Block = 128 i-rows x 128 j-cols, 4 waves in 2x2; each wave computes a
// 64x64 sub-tile as 4x4 grid of 16x16x32 bf16 MFMAs. BK=32, single-buffer
// LDS staged via global_load_lds width=16 (wave-uniform LDS base + lane*16;
// LDS layout therefore row-major [row][BK], unpadded — required by HW).
__global__ __launch_bounds__(256) void k_gemm_sumexp(
    const unsigned short* __restrict__ z1b, const unsigned short* __restrict__ z2b,
    float* __restrict__ S) {
    __shared__ unsigned short As[128 * BK];  // 8 KB
    __shared__ unsigned short Bs[128 * BK];  // 8 KB

    const int iT = blockIdx.y, jT = blockIdx.x;
    const int lane = threadIdx.x & 63, wave = threadIdx.x >> 6;
    const int wm = wave >> 1, wn = wave & 1;     // 2x2 wave grid
    const int ml = lane & 15, q = lane >> 4;     // MFMA lane decomposition
    const int i0 = iT * 128, j0 = jT * 128;

    // staging decomposition: chunk = 16 rows x 32 elems = 1 KB = one wave-issue.
    // lane covers row (lane>>2) of the chunk, elements (lane&3)*8 .. +7.
    const int sr = lane >> 2;
    const int sc = (lane & 3) * 8;

    floatx4 acc[4][4];
    #pragma unroll
    for (int mt = 0; mt < 4; ++mt)
        #pragma unroll
        for (int nt = 0; nt < 4; ++nt)
            acc[mt][nt] = (floatx4){0.f, 0.f, 0.f, 0.f};

    for (int k0 = 0; k0 < DIM; k0 += BK) {
        #pragma unroll
        for (int c = 0; c < 2; ++c) {
            const int chunk = wave * 2 + c;          // 0..7
            const int row = chunk * 16 + sr;         // 0..127
            const unsigned short* gA = z1b + (size_t)(i0 + row) * DIM + k0 + sc;
            const unsigned short* gB = z2b + (size_t)(j0 + row) * DIM + k0 + sc;
            __builtin_amdgcn_global_load_lds(
                (const __attribute__((address_space(1))) void*)gA,
                (__attribute__((address_space(3))) void*)(As + chunk * 512), 16, 0, 0);
            __builtin_amdgcn_global_load_lds(
                (const __attribute__((address_space(1))) void*)gB,
                (__attribute__((address_space(3))) void*)(Bs + chunk * 512), 16, 0, 0);
        }
        __syncthreads();

        short8 af[4], bf[4];
        #pragma unroll
        for (int t = 0; t < 4; ++t) {
            af[t] = *reinterpret_cast<const short8*>(As + (wm * 64 + t * 16 + ml) * BK + q * 8);
            bf[t] = *reinterpret_cast<const short8*>(Bs + (wn * 64 + t * 16 + ml) * BK + q * 8);
        }
        #pragma unroll
        for (int mt = 0; mt < 4; ++mt)
            #pragma unroll
            for (int nt = 0; nt < 4; ++nt)
                acc[mt][nt] = __builtin_amdgcn_mfma_f32_16x16x32_bf16(
                    af[mt], bf[nt], acc[mt][nt], 0, 0, 0);
        __syncthreads();
    }

    // Epilogue: C/D layout col=lane&15, row=q*4+reg. Fuse exp + row-sum over
    // this wave's 64 columns, reduce across the 16 ml-lanes, one atomic per row.
    #pragma unroll
    for (int mt = 0; mt < 4; ++mt) {
        #pragma unroll
        for (int r = 0; r < 4; ++r) {
            float v = 0.f;
            #pragma unroll
            for (int nt = 0; nt < 4; ++nt)
                v += __expf(acc[mt][nt][r] * INV_T);
            v += __shfl_xor(v, 1, 64);
            v += __shfl_xor(v, 2, 64);
            v += __shfl_xor(v, 4, 64);
            v += __shfl_xor(v, 8, 64);
            if (ml == 0)
                atomicAdd(&S[i0 + wm * 64 + mt * 16 + q * 4 + r], v);
        }
    }
}

__global__ __launch_bounds__(256) void k_finalize(
    const float* __restrict__ S, const float* __restrict__ diag,
    float* __restrict__ out) {
    const int t = threadIdx.x;
    float acc = 0.f;
    for (int i = t; i < N_ROWS; i += 256)
        acc += logf(S[i]) - diag[i];
    #pragma unroll
    for (int m = 32; m >= 1; m >>= 1)
        acc += __shfl_xor(acc, m, 64);
    __shared__ float r[4];
    if ((t & 63) == 0) r[t >> 6] = acc;
    __syncthreads();
    if (t == 0) out[0] = (r[0] + r[1] + r[2] + r[3]) / (float)N_ROWS;
}

extern "C" void kernel_launch(void* const* d_in, const int* in_sizes, int n_in,
                              void* d_out, int out_size, void* d_ws, size_t ws_size,
                              hipStream_t stream) {
    const float* z1 = (const float*)d_in[0];
    const float* z2 = (const float*)d_in[1];

    char* ws = (char*)d_ws;
    unsigned short* z1b = (unsigned short*)ws;                                   // 8 MB
    unsigned short* z2b = (unsigned short*)(ws + (size_t)N_ROWS * DIM * 2);      // 8 MB
    float* diag = (float*)(ws + (size_t)N_ROWS * DIM * 4);                       // 16 KB
    float* S = diag + N_ROWS;                                                    // 16 KB

    hipMemsetAsync(S, 0, N_ROWS * sizeof(float), stream);
    k_normalize<<<N_ROWS, 256, 0, stream>>>(z1, z2, z1b, z2b, diag);
    k_gemm_sumexp<<<dim3(32, 32), 256, 0, stream>>>(z1b, z2b, S);
    k_finalize<<<1, 256, 0, stream>>>(S, diag, (float*)d_out);
}